// Round 1
// baseline (279.423 us; speedup 1.0000x reference)
//
#include <hip/hip_runtime.h>

typedef __bf16 bf16;
typedef __attribute__((ext_vector_type(8))) __bf16 bf16x8;
typedef __attribute__((ext_vector_type(4))) float floatx4;

#define TOK 2048
#define DD  1024
#define NE  8
// logical N (out features of each GEMM) = 1023, padded to 1024

__device__ __forceinline__ uint4 pack_bf8(float4 a, float4 b) {
  union { bf16 h[8]; uint4 u; } p;
  p.h[0] = (bf16)a.x; p.h[1] = (bf16)a.y; p.h[2] = (bf16)a.z; p.h[3] = (bf16)a.w;
  p.h[4] = (bf16)b.x; p.h[5] = (bf16)b.y; p.h[6] = (bf16)b.z; p.h[7] = (bf16)b.w;
  return p.u;
}

// ---------------- gate + x->bf16 ----------------
__global__ __launch_bounds__(256) void gate_cvt_kernel(
    const float* __restrict__ x, const float* __restrict__ gate_w,
    const float* __restrict__ gate_b, bf16* __restrict__ x_bf,
    int* __restrict__ eidx, float* __restrict__ ewgt)
{
  const int t = blockIdx.x, tid = threadIdx.x;
  const float4 v = ((const float4*)(x + (size_t)t * DD))[tid];
  union { bf16 h[4]; uint2 u; } pk;
  pk.h[0] = (bf16)v.x; pk.h[1] = (bf16)v.y; pk.h[2] = (bf16)v.z; pk.h[3] = (bf16)v.w;
  ((uint2*)(x_bf + (size_t)t * DD))[tid] = pk.u;

  float acc[NE];
#pragma unroll
  for (int e = 0; e < NE; ++e) acc[e] = 0.f;
  const float vv[4] = {v.x, v.y, v.z, v.w};
#pragma unroll
  for (int i = 0; i < 4; ++i) {
    const int d = tid * 4 + i;
    if (d >= 1) {
#pragma unroll
      for (int e = 0; e < NE; ++e) acc[e] += vv[i] * gate_w[e * (DD - 1) + d - 1];
    }
  }
#pragma unroll
  for (int off = 32; off > 0; off >>= 1) {
#pragma unroll
    for (int e = 0; e < NE; ++e) acc[e] += __shfl_down(acc[e], off);
  }
  __shared__ float red[4][NE];
  const int wid = tid >> 6, lane = tid & 63;
  if (lane == 0) {
#pragma unroll
    for (int e = 0; e < NE; ++e) red[wid][e] = acc[e];
  }
  __syncthreads();
  if (tid == 0) {
    float lg[NE];
#pragma unroll
    for (int e = 0; e < NE; ++e) lg[e] = red[0][e] + red[1][e] + red[2][e] + red[3][e];
    float m = lg[0];
    for (int e = 1; e < NE; ++e) m = fmaxf(m, lg[e]);
    float ex[NE], s = 0.f;
    for (int e = 0; e < NE; ++e) { ex[e] = expf(lg[e] - m); s += ex[e]; }
    const float inv = 1.f / s;
    int best = 0; float bb = ex[0] * inv + gate_b[0];
    for (int e = 1; e < NE; ++e) {
      const float b = ex[e] * inv + gate_b[e];
      if (b > bb) { bb = b; best = e; }
    }
    eidx[t] = best;
    ewgt[t] = ex[best] * inv;
  }
}

// ---------------- routing: count + prefix + scatter ----------------
__global__ __launch_bounds__(256) void route_kernel(
    const int* __restrict__ eidx, int* __restrict__ perm,
    int* __restrict__ pos_of, int* __restrict__ seg_base)
{
  __shared__ int cnt[NE], off[NE], bas[NE + 1];
  const int tid = threadIdx.x;
  if (tid < NE) cnt[tid] = 0;
  __syncthreads();
  for (int t = tid; t < TOK; t += 256) atomicAdd(&cnt[eidx[t]], 1);
  __syncthreads();
  if (tid == 0) {
    int run = 0;
    for (int e = 0; e < NE; ++e) { bas[e] = run; off[e] = run; run += cnt[e]; }
    bas[NE] = run;
  }
  __syncthreads();
  for (int t = tid; t < TOK; t += 256) {
    const int e = eidx[t];
    const int p = atomicAdd(&off[e], 1);
    perm[p] = t;
    pos_of[t] = p;
  }
  if (tid <= NE) seg_base[tid] = bas[tid];
}

// ---------------- mlp1: dual GEMM (W1,W3) + silu-gate + h(bf16) + sumsq ----------------
// grid: x = 16 (N tiles of 64), y = 144 (8 experts * 16 m-tiles + 16 shared m-tiles)
__global__ __launch_bounds__(256) void mlp1_kernel(
    const bf16* __restrict__ x_bf,
    const float* __restrict__ W1, const float* __restrict__ W3,
    const float* __restrict__ Ws1, const float* __restrict__ Ws3,
    const int* __restrict__ perm, const int* __restrict__ seg_base,
    bf16* __restrict__ h_r, bf16* __restrict__ h_s,
    float* __restrict__ ss_r, float* __restrict__ ss_z)
{
  const int nt = blockIdx.x;
  const int mslot = blockIdx.y;
  const int tid = threadIdx.x;
  int base, cnt, row0;
  const float *w1p, *w3p;
  const int* permp;
  bf16* hbuf;
  float* ssbuf;
  if (mslot < 128) {
    const int e = mslot >> 4;
    base = seg_base[e];
    cnt  = seg_base[e + 1] - base;
    row0 = (mslot & 15) * 128;
    if (row0 >= cnt) return;
    w1p = W1 + (size_t)e * 1023 * 1024;
    w3p = W3 + (size_t)e * 1023 * 1024;
    permp = perm; hbuf = h_r; ssbuf = ss_r;
  } else {
    base = 0; cnt = TOK; row0 = (mslot - 128) * 128;
    w1p = Ws1; w3p = Ws3;
    permp = nullptr; hbuf = h_s; ssbuf = ss_z;
  }
  const int n0 = nt * 64;

  __shared__ __align__(16) bf16 As[128 * 32];
  __shared__ __align__(16) bf16 B1s[64 * 32];
  __shared__ __align__(16) bf16 B3s[64 * 32];
  __shared__ int toks[128];

  if (tid < 128) {
    int r = row0 + tid;
    if (r >= cnt) r = cnt - 1;
    toks[tid] = permp ? permp[base + r] : r;
  }
  __syncthreads();

  const int arow = tid >> 1, acol = (tid & 1) * 16;
  const bf16* aptr = x_bf + (size_t)toks[arow] * DD + acol;
  bf16* const alds = As + arow * 32 + acol;

  const int brow = tid >> 2, bcol = (tid & 3) * 8;
  int bn = n0 + brow; if (bn > 1022) bn = 1022;
  const float* b1ptr = w1p + (size_t)bn * 1024 + bcol;
  const float* b3ptr = w3p + (size_t)bn * 1024 + bcol;
  bf16* const b1lds = B1s + brow * 32 + bcol;
  bf16* const b3lds = B3s + brow * 32 + bcol;

  const int wid = tid >> 6, lane = tid & 63;
  const int wr = (wid >> 1) * 64, wc = (wid & 1) * 32;
  const int lrow = lane & 15, quad = lane >> 4;

  const floatx4 fz = {0.f, 0.f, 0.f, 0.f};
  floatx4 acc1[4][2], acc3[4][2];
#pragma unroll
  for (int mi = 0; mi < 4; ++mi)
#pragma unroll
    for (int ni = 0; ni < 2; ++ni) { acc1[mi][ni] = fz; acc3[mi][ni] = fz; }

  for (int k0 = 0; k0 < 1024; k0 += 32) {
    const uint4  a0  = *(const uint4*)(aptr + k0);
    const uint4  a1  = *(const uint4*)(aptr + k0 + 8);
    const float4 f10 = *(const float4*)(b1ptr + k0);
    const float4 f11 = *(const float4*)(b1ptr + k0 + 4);
    const float4 f30 = *(const float4*)(b3ptr + k0);
    const float4 f31 = *(const float4*)(b3ptr + k0 + 4);
    __syncthreads();
    *(uint4*)alds       = a0;
    *(uint4*)(alds + 8) = a1;
    *(uint4*)b1lds = pack_bf8(f10, f11);
    *(uint4*)b3lds = pack_bf8(f30, f31);
    __syncthreads();
    bf16x8 af[4], b1f[2], b3f[2];
#pragma unroll
    for (int mi = 0; mi < 4; ++mi)
      af[mi] = *(const bf16x8*)(As + (wr + mi * 16 + lrow) * 32 + quad * 8);
#pragma unroll
    for (int ni = 0; ni < 2; ++ni) {
      b1f[ni] = *(const bf16x8*)(B1s + (wc + ni * 16 + lrow) * 32 + quad * 8);
      b3f[ni] = *(const bf16x8*)(B3s + (wc + ni * 16 + lrow) * 32 + quad * 8);
    }
#pragma unroll
    for (int mi = 0; mi < 4; ++mi)
#pragma unroll
      for (int ni = 0; ni < 2; ++ni) {
        acc1[mi][ni] = __builtin_amdgcn_mfma_f32_16x16x32_bf16(af[mi], b1f[ni], acc1[mi][ni], 0, 0, 0);
        acc3[mi][ni] = __builtin_amdgcn_mfma_f32_16x16x32_bf16(af[mi], b3f[ni], acc3[mi][ni], 0, 0, 0);
      }
  }

  const int mbase = base + row0;
#pragma unroll
  for (int mi = 0; mi < 4; ++mi) {
#pragma unroll
    for (int r = 0; r < 4; ++r) {
      const int row = wr + mi * 16 + quad * 4 + r;
      const bool rowok = (row0 + row) < cnt;
      float ssum = 0.f;
#pragma unroll
      for (int ni = 0; ni < 2; ++ni) {
        const float s1 = acc1[mi][ni][r];
        const float s3 = acc3[mi][ni][r];
        const float sp = (s1 / (1.f + __expf(-s1))) * s3;  // silu(s1)*s3
        const int n = n0 + wc + ni * 16 + lrow;
        if (rowok && n < 1023) {
          hbuf[(size_t)(mbase + row) * 1024 + 1 + n] = (bf16)sp;
          ssum += sp * sp;
        }
      }
      ssum += __shfl_xor(ssum, 1);
      ssum += __shfl_xor(ssum, 2);
      ssum += __shfl_xor(ssum, 4);
      ssum += __shfl_xor(ssum, 8);
      if (lrow == 0 && rowok) atomicAdd(ssbuf + mbase + row, ssum);
    }
  }
}

// ---------------- h[:,0] = sqrt(sumsq + 1) ----------------
__global__ __launch_bounds__(256) void finalize_t_kernel(
    const float* __restrict__ ss_r, const float* __restrict__ ss_z,
    bf16* __restrict__ h_r, bf16* __restrict__ h_s)
{
  const int i = blockIdx.x * 256 + threadIdx.x;
  if (i < TOK) {
    h_r[(size_t)i * 1024] = (bf16)sqrtf(ss_r[i] + 1.0f);
    h_s[(size_t)i * 1024] = (bf16)sqrtf(ss_z[i] + 1.0f);
  }
}

// ---------------- mlp2: o = h @ W2^T (fp32 out) + sumsq ----------------
// grid: x = 8 (N tiles of 128), y = 144
__global__ __launch_bounds__(256) void mlp2_kernel(
    const bf16* __restrict__ h_r, const bf16* __restrict__ h_s,
    const float* __restrict__ W2, const float* __restrict__ Ws2,
    const int* __restrict__ seg_base,
    float* __restrict__ o_r, float* __restrict__ o_s,
    float* __restrict__ ss_or, float* __restrict__ ss_oz)
{
  const int nt = blockIdx.x;
  const int mslot = blockIdx.y;
  const int tid = threadIdx.x;
  int base, cnt, row0;
  const float* wp;
  const bf16* abuf;
  float *obuf, *ssbuf;
  if (mslot < 128) {
    const int e = mslot >> 4;
    base = seg_base[e];
    cnt  = seg_base[e + 1] - base;
    row0 = (mslot & 15) * 128;
    if (row0 >= cnt) return;
    wp = W2 + (size_t)e * 1023 * 1024;
    abuf = h_r; obuf = o_r; ssbuf = ss_or;
  } else {
    base = 0; cnt = TOK; row0 = (mslot - 128) * 128;
    wp = Ws2; abuf = h_s; obuf = o_s; ssbuf = ss_oz;
  }
  const int n0 = nt * 128;

  __shared__ __align__(16) bf16 As[128 * 32];
  __shared__ __align__(16) bf16 Bs[128 * 32];

  const int arow = tid >> 1, acol = (tid & 1) * 16;
  int ar = row0 + arow; if (ar >= cnt) ar = cnt - 1;
  const bf16* aptr = abuf + (size_t)(base + ar) * 1024 + acol;
  bf16* const alds = As + arow * 32 + acol;

  const int brow = tid >> 1, bcol = (tid & 1) * 16;
  int bn = n0 + brow; if (bn > 1022) bn = 1022;
  const float* bptr = wp + (size_t)bn * 1024 + bcol;
  bf16* const blds = Bs + brow * 32 + bcol;

  const int wid = tid >> 6, lane = tid & 63;
  const int wr = (wid >> 1) * 64, wc = (wid & 1) * 64;
  const int lrow = lane & 15, quad = lane >> 4;

  const floatx4 fz = {0.f, 0.f, 0.f, 0.f};
  floatx4 acc[4][4];
#pragma unroll
  for (int mi = 0; mi < 4; ++mi)
#pragma unroll
    for (int ni = 0; ni < 4; ++ni) acc[mi][ni] = fz;

  for (int k0 = 0; k0 < 1024; k0 += 32) {
    const uint4  a0 = *(const uint4*)(aptr + k0);
    const uint4  a1 = *(const uint4*)(aptr + k0 + 8);
    const float4 f0 = *(const float4*)(bptr + k0);
    const float4 f1 = *(const float4*)(bptr + k0 + 4);
    const float4 f2 = *(const float4*)(bptr + k0 + 8);
    const float4 f3 = *(const float4*)(bptr + k0 + 12);
    __syncthreads();
    *(uint4*)alds       = a0;
    *(uint4*)(alds + 8) = a1;
    *(uint4*)blds       = pack_bf8(f0, f1);
    *(uint4*)(blds + 8) = pack_bf8(f2, f3);
    __syncthreads();
    bf16x8 af[4], bf_[4];
#pragma unroll
    for (int mi = 0; mi < 4; ++mi)
      af[mi] = *(const bf16x8*)(As + (wr + mi * 16 + lrow) * 32 + quad * 8);
#pragma unroll
    for (int ni = 0; ni < 4; ++ni)
      bf_[ni] = *(const bf16x8*)(Bs + (wc + ni * 16 + lrow) * 32 + quad * 8);
#pragma unroll
    for (int mi = 0; mi < 4; ++mi)
#pragma unroll
      for (int ni = 0; ni < 4; ++ni)
        acc[mi][ni] = __builtin_amdgcn_mfma_f32_16x16x32_bf16(af[mi], bf_[ni], acc[mi][ni], 0, 0, 0);
  }

  const int mbase = base + row0;
#pragma unroll
  for (int mi = 0; mi < 4; ++mi) {
#pragma unroll
    for (int r = 0; r < 4; ++r) {
      const int row = wr + mi * 16 + quad * 4 + r;
      const bool rowok = (row0 + row) < cnt;
      float ssum = 0.f;
#pragma unroll
      for (int ni = 0; ni < 4; ++ni) {
        const float v = acc[mi][ni][r];
        const int n = n0 + wc + ni * 16 + lrow;
        if (rowok && n < 1023) {
          obuf[(size_t)(mbase + row) * 1024 + n] = v;
          ssum += v * v;
        }
      }
      ssum += __shfl_xor(ssum, 1);
      ssum += __shfl_xor(ssum, 2);
      ssum += __shfl_xor(ssum, 4);
      ssum += __shfl_xor(ssum, 8);
      if (lrow == 0 && rowok) atomicAdd(ssbuf + mbase + row, ssum);
    }
  }
}

// ---------------- final LResNet combine + Lorentz normalize ----------------
__global__ __launch_bounds__(256) void combine_kernel(
    const float* __restrict__ o_r, const float* __restrict__ o_s,
    const float* __restrict__ ss_or, const float* __restrict__ ss_oz,
    const int* __restrict__ pos_of, const float* __restrict__ wgt,
    float* __restrict__ out)
{
  const int t = blockIdx.x, tid = threadIdx.x;
  const int p = pos_of[t];
  const float w = wgt[t];
  const float4 oz = ((const float4*)(o_s + (size_t)t * 1024))[tid];
  const float4 oe = ((const float4*)(o_r + (size_t)p * 1024))[tid];
  const float tw = 2.f * w;
  float c0 = oz.x + tw * oe.x;
  float c1 = oz.y + tw * oe.y;
  float c2 = oz.z + tw * oe.z;
  float c3 = (tid == 255) ? 0.f : (oz.w + tw * oe.w);  // n=1023 is padding
  float ssum = c0 * c0 + c1 * c1 + c2 * c2 + c3 * c3;
#pragma unroll
  for (int off = 32; off > 0; off >>= 1) ssum += __shfl_down(ssum, off);
  __shared__ float rs[4];
  if ((tid & 63) == 0) rs[tid >> 6] = ssum;
  __syncthreads();
  const float space2 = rs[0] + rs[1] + rs[2] + rs[3];
  const float comb0 = sqrtf(ss_oz[t] + 1.f) + 2.f + 2.f * w * sqrtf(ss_or[p] + 1.f);
  const float li = space2 - comb0 * comb0;
  const float inv = 1.f / sqrtf(fmaxf(fabsf(li), 1e-8f));
  float* orow = out + (size_t)t * 1024;
  const int j = 1 + tid * 4;
  orow[j]     = c0 * inv;
  orow[j + 1] = c1 * inv;
  orow[j + 2] = c2 * inv;
  if (tid != 255) orow[j + 3] = c3 * inv;
  if (tid == 0) orow[0] = comb0 * inv;
}

extern "C" void kernel_launch(void* const* d_in, const int* in_sizes, int n_in,
                              void* d_out, int out_size, void* d_ws, size_t ws_size,
                              hipStream_t stream) {
  const float* x      = (const float*)d_in[0];
  const float* gate_w = (const float*)d_in[1];
  const float* gate_b = (const float*)d_in[2];
  const float* W1     = (const float*)d_in[3];
  const float* W3     = (const float*)d_in[4];
  const float* W2     = (const float*)d_in[5];
  const float* Ws1    = (const float*)d_in[6];
  const float* Ws3    = (const float*)d_in[7];
  const float* Ws2    = (const float*)d_in[8];
  float* out = (float*)d_out;

  char* ws = (char*)d_ws;
  size_t off = 0;
  auto alloc = [&](size_t bytes) {
    void* p = ws + off;
    off += (bytes + 255) & ~(size_t)255;
    return p;
  };
  bf16*  x_bf = (bf16*) alloc((size_t)TOK * 1024 * 2);
  bf16*  h_r  = (bf16*) alloc((size_t)TOK * 1024 * 2);
  bf16*  h_s  = (bf16*) alloc((size_t)TOK * 1024 * 2);
  float* o_r  = (float*)alloc((size_t)TOK * 1024 * 4);
  float* o_s  = (float*)alloc((size_t)TOK * 1024 * 4);
  float* ss   = (float*)alloc((size_t)4 * TOK * 4);  // ss_r, ss_z, ss_or, ss_oz
  int*   eidx = (int*)  alloc((size_t)TOK * 4);
  float* ewgt = (float*)alloc((size_t)TOK * 4);
  int*   perm = (int*)  alloc((size_t)TOK * 4);
  int*   posf = (int*)  alloc((size_t)TOK * 4);
  int*   segb = (int*)  alloc(64);

  float* ss_r  = ss;
  float* ss_z  = ss + TOK;
  float* ss_or = ss + 2 * TOK;
  float* ss_oz = ss + 3 * TOK;

  hipMemsetAsync(ss, 0, (size_t)4 * TOK * 4, stream);
  gate_cvt_kernel<<<TOK, 256, 0, stream>>>(x, gate_w, gate_b, x_bf, eidx, ewgt);
  route_kernel<<<1, 256, 0, stream>>>(eidx, perm, posf, segb);
  mlp1_kernel<<<dim3(16, 144), 256, 0, stream>>>(x_bf, W1, W3, Ws1, Ws3, perm, segb,
                                                 h_r, h_s, ss_r, ss_z);
  finalize_t_kernel<<<8, 256, 0, stream>>>(ss_r, ss_z, h_r, h_s);
  mlp2_kernel<<<dim3(8, 144), 256, 0, stream>>>(h_r, h_s, W2, Ws2, segb,
                                                o_r, o_s, ss_or, ss_oz);
  combine_kernel<<<TOK, 256, 0, stream>>>(o_r, o_s, ss_or, ss_oz, posf, ewgt, out);
}

// Round 2
// 278.618 us; speedup vs baseline: 1.0029x; 1.0029x over previous
//
#include <hip/hip_runtime.h>

typedef __bf16 bf16;
typedef __attribute__((ext_vector_type(8))) __bf16 bf16x8;
typedef __attribute__((ext_vector_type(4))) float floatx4;

#define TOK 2048
#define DD  1024
#define NE  8
#define LDA 40   // padded LDS row stride (bf16 elements): 80 B -> conflict-free-ish

__device__ __forceinline__ uint4 pack_bf8(float4 a, float4 b) {
  union { bf16 h[8]; uint4 u; } p;
  p.h[0] = (bf16)a.x; p.h[1] = (bf16)a.y; p.h[2] = (bf16)a.z; p.h[3] = (bf16)a.w;
  p.h[4] = (bf16)b.x; p.h[5] = (bf16)b.y; p.h[6] = (bf16)b.z; p.h[7] = (bf16)b.w;
  return p.u;
}

// ---------------- gate + x->bf16 ----------------
__global__ __launch_bounds__(256) void gate_cvt_kernel(
    const float* __restrict__ x, const float* __restrict__ gate_w,
    const float* __restrict__ gate_b, bf16* __restrict__ x_bf,
    int* __restrict__ eidx, float* __restrict__ ewgt)
{
  const int t = blockIdx.x, tid = threadIdx.x;
  const float4 v = ((const float4*)(x + (size_t)t * DD))[tid];
  union { bf16 h[4]; uint2 u; } pk;
  pk.h[0] = (bf16)v.x; pk.h[1] = (bf16)v.y; pk.h[2] = (bf16)v.z; pk.h[3] = (bf16)v.w;
  ((uint2*)(x_bf + (size_t)t * DD))[tid] = pk.u;

  float acc[NE];
#pragma unroll
  for (int e = 0; e < NE; ++e) acc[e] = 0.f;
  const float vv[4] = {v.x, v.y, v.z, v.w};
#pragma unroll
  for (int i = 0; i < 4; ++i) {
    const int d = tid * 4 + i;
    if (d >= 1) {
#pragma unroll
      for (int e = 0; e < NE; ++e) acc[e] += vv[i] * gate_w[e * (DD - 1) + d - 1];
    }
  }
#pragma unroll
  for (int off = 32; off > 0; off >>= 1) {
#pragma unroll
    for (int e = 0; e < NE; ++e) acc[e] += __shfl_down(acc[e], off);
  }
  __shared__ float red[4][NE];
  const int wid = tid >> 6, lane = tid & 63;
  if (lane == 0) {
#pragma unroll
    for (int e = 0; e < NE; ++e) red[wid][e] = acc[e];
  }
  __syncthreads();
  if (tid == 0) {
    float lg[NE];
#pragma unroll
    for (int e = 0; e < NE; ++e) lg[e] = red[0][e] + red[1][e] + red[2][e] + red[3][e];
    float m = lg[0];
    for (int e = 1; e < NE; ++e) m = fmaxf(m, lg[e]);
    float ex[NE], s = 0.f;
    for (int e = 0; e < NE; ++e) { ex[e] = expf(lg[e] - m); s += ex[e]; }
    const float inv = 1.f / s;
    int best = 0; float bb = ex[0] * inv + gate_b[0];
    for (int e = 1; e < NE; ++e) {
      const float b = ex[e] * inv + gate_b[e];
      if (b > bb) { bb = b; best = e; }
    }
    eidx[t] = best;
    ewgt[t] = ex[best] * inv;
  }
}

// ---------------- routing: count + prefix + scatter ----------------
__global__ __launch_bounds__(256) void route_kernel(
    const int* __restrict__ eidx, int* __restrict__ perm,
    int* __restrict__ pos_of, int* __restrict__ seg_base)
{
  __shared__ int cnt[NE], off[NE], bas[NE + 1];
  const int tid = threadIdx.x;
  if (tid < NE) cnt[tid] = 0;
  __syncthreads();
  for (int t = tid; t < TOK; t += 256) atomicAdd(&cnt[eidx[t]], 1);
  __syncthreads();
  if (tid == 0) {
    int run = 0;
    for (int e = 0; e < NE; ++e) { bas[e] = run; off[e] = run; run += cnt[e]; }
    bas[NE] = run;
  }
  __syncthreads();
  for (int t = tid; t < TOK; t += 256) {
    const int e = eidx[t];
    const int p = atomicAdd(&off[e], 1);
    perm[p] = t;
    pos_of[t] = p;
  }
  if (tid <= NE) seg_base[tid] = bas[tid];
}

// ---------------- mlp1: dual GEMM (W1,W3) + silu-gate + h(bf16) + sumsq ----------------
// grid: x = 16 (N tiles of 64), y = 144 (8 experts * 16 m-tiles + 16 shared m-tiles)
__global__ __launch_bounds__(256) void mlp1_kernel(
    const bf16* __restrict__ x_bf,
    const float* __restrict__ W1, const float* __restrict__ W3,
    const float* __restrict__ Ws1, const float* __restrict__ Ws3,
    const int* __restrict__ perm, const int* __restrict__ seg_base,
    bf16* __restrict__ h_r, bf16* __restrict__ h_s,
    float* __restrict__ ss_r, float* __restrict__ ss_z)
{
  const int nt = blockIdx.x;
  const int mslot = blockIdx.y;
  const int tid = threadIdx.x;
  int base, cnt, row0;
  const float *w1p, *w3p;
  const int* permp;
  bf16* hbuf;
  float* ssbuf;
  if (mslot < 128) {
    const int e = mslot >> 4;
    base = seg_base[e];
    cnt  = seg_base[e + 1] - base;
    row0 = (mslot & 15) * 128;
    if (row0 >= cnt) return;
    w1p = W1 + (size_t)e * 1023 * 1024;
    w3p = W3 + (size_t)e * 1023 * 1024;
    permp = perm; hbuf = h_r; ssbuf = ss_r;
  } else {
    base = 0; cnt = TOK; row0 = (mslot - 128) * 128;
    w1p = Ws1; w3p = Ws3;
    permp = nullptr; hbuf = h_s; ssbuf = ss_z;
  }
  const int n0 = nt * 64;

  __shared__ __align__(16) bf16 As[128 * LDA];
  __shared__ __align__(16) bf16 B1s[64 * LDA];
  __shared__ __align__(16) bf16 B3s[64 * LDA];
  __shared__ int toks[128];

  if (tid < 128) {
    int r = row0 + tid;
    if (r >= cnt) r = cnt - 1;
    toks[tid] = permp ? permp[base + r] : r;
  }
  __syncthreads();

  const int arow = tid >> 1, acol = (tid & 1) * 16;
  const bf16* aptr = x_bf + (size_t)toks[arow] * DD + acol;
  bf16* const alds = As + arow * LDA + acol;

  const int brow = tid >> 2, bcol = (tid & 3) * 8;
  int bn = n0 + brow; if (bn > 1022) bn = 1022;
  const float* b1ptr = w1p + (size_t)bn * 1024 + bcol;
  const float* b3ptr = w3p + (size_t)bn * 1024 + bcol;
  bf16* const b1lds = B1s + brow * LDA + bcol;
  bf16* const b3lds = B3s + brow * LDA + bcol;

  const int wid = tid >> 6, lane = tid & 63;
  const int wr = (wid >> 1) * 64, wc = (wid & 1) * 32;
  const int lrow = lane & 15, quad = lane >> 4;

  const floatx4 fz = {0.f, 0.f, 0.f, 0.f};
  floatx4 acc1[4][2], acc3[4][2];
#pragma unroll
  for (int mi = 0; mi < 4; ++mi)
#pragma unroll
    for (int ni = 0; ni < 2; ++ni) { acc1[mi][ni] = fz; acc3[mi][ni] = fz; }

  // register prefetch (double-buffered in VGPRs)
  uint4  a0  = *(const uint4*)(aptr);
  uint4  a1  = *(const uint4*)(aptr + 8);
  float4 f10 = *(const float4*)(b1ptr);
  float4 f11 = *(const float4*)(b1ptr + 4);
  float4 f30 = *(const float4*)(b3ptr);
  float4 f31 = *(const float4*)(b3ptr + 4);

  for (int k0 = 0; k0 < 1024; k0 += 32) {
    __syncthreads();
    *(uint4*)alds       = a0;
    *(uint4*)(alds + 8) = a1;
    *(uint4*)b1lds = pack_bf8(f10, f11);
    *(uint4*)b3lds = pack_bf8(f30, f31);
    __syncthreads();
    // issue next iteration's global loads NOW so they overlap the MFMA stage
    const int kn = (k0 + 32 < 1024) ? (k0 + 32) : 0;
    a0  = *(const uint4*)(aptr + kn);
    a1  = *(const uint4*)(aptr + kn + 8);
    f10 = *(const float4*)(b1ptr + kn);
    f11 = *(const float4*)(b1ptr + kn + 4);
    f30 = *(const float4*)(b3ptr + kn);
    f31 = *(const float4*)(b3ptr + kn + 4);

    bf16x8 af[4], b1f[2], b3f[2];
#pragma unroll
    for (int mi = 0; mi < 4; ++mi)
      af[mi] = *(const bf16x8*)(As + (wr + mi * 16 + lrow) * LDA + quad * 8);
#pragma unroll
    for (int ni = 0; ni < 2; ++ni) {
      b1f[ni] = *(const bf16x8*)(B1s + (wc + ni * 16 + lrow) * LDA + quad * 8);
      b3f[ni] = *(const bf16x8*)(B3s + (wc + ni * 16 + lrow) * LDA + quad * 8);
    }
#pragma unroll
    for (int mi = 0; mi < 4; ++mi)
#pragma unroll
      for (int ni = 0; ni < 2; ++ni) {
        acc1[mi][ni] = __builtin_amdgcn_mfma_f32_16x16x32_bf16(af[mi], b1f[ni], acc1[mi][ni], 0, 0, 0);
        acc3[mi][ni] = __builtin_amdgcn_mfma_f32_16x16x32_bf16(af[mi], b3f[ni], acc3[mi][ni], 0, 0, 0);
      }
  }

  const int mbase = base + row0;
#pragma unroll
  for (int mi = 0; mi < 4; ++mi) {
#pragma unroll
    for (int r = 0; r < 4; ++r) {
      const int row = wr + mi * 16 + quad * 4 + r;
      const bool rowok = (row0 + row) < cnt;
      float ssum = 0.f;
#pragma unroll
      for (int ni = 0; ni < 2; ++ni) {
        const float s1 = acc1[mi][ni][r];
        const float s3 = acc3[mi][ni][r];
        const float sp = (s1 / (1.f + __expf(-s1))) * s3;  // silu(s1)*s3
        const int n = n0 + wc + ni * 16 + lrow;
        if (rowok && n < 1023) {
          hbuf[(size_t)(mbase + row) * 1024 + 1 + n] = (bf16)sp;
          ssum += sp * sp;
        }
      }
      ssum += __shfl_xor(ssum, 1);
      ssum += __shfl_xor(ssum, 2);
      ssum += __shfl_xor(ssum, 4);
      ssum += __shfl_xor(ssum, 8);
      if (lrow == 0 && rowok) atomicAdd(ssbuf + mbase + row, ssum);
    }
  }
}

// ---------------- h[:,0] = sqrt(sumsq + 1) ----------------
__global__ __launch_bounds__(256) void finalize_t_kernel(
    const float* __restrict__ ss_r, const float* __restrict__ ss_z,
    bf16* __restrict__ h_r, bf16* __restrict__ h_s)
{
  const int i = blockIdx.x * 256 + threadIdx.x;
  if (i < TOK) {
    h_r[(size_t)i * 1024] = (bf16)sqrtf(ss_r[i] + 1.0f);
    h_s[(size_t)i * 1024] = (bf16)sqrtf(ss_z[i] + 1.0f);
  }
}

// ---------------- mlp2: o = h @ W2^T (fp32 out) + sumsq ----------------
// grid: x = 8 (N tiles of 128), y = 144
__global__ __launch_bounds__(256) void mlp2_kernel(
    const bf16* __restrict__ h_r, const bf16* __restrict__ h_s,
    const float* __restrict__ W2, const float* __restrict__ Ws2,
    const int* __restrict__ seg_base,
    float* __restrict__ o_r, float* __restrict__ o_s,
    float* __restrict__ ss_or, float* __restrict__ ss_oz)
{
  const int nt = blockIdx.x;
  const int mslot = blockIdx.y;
  const int tid = threadIdx.x;
  int base, cnt, row0;
  const float* wp;
  const bf16* abuf;
  float *obuf, *ssbuf;
  if (mslot < 128) {
    const int e = mslot >> 4;
    base = seg_base[e];
    cnt  = seg_base[e + 1] - base;
    row0 = (mslot & 15) * 128;
    if (row0 >= cnt) return;
    wp = W2 + (size_t)e * 1023 * 1024;
    abuf = h_r; obuf = o_r; ssbuf = ss_or;
  } else {
    base = 0; cnt = TOK; row0 = (mslot - 128) * 128;
    wp = Ws2; abuf = h_s; obuf = o_s; ssbuf = ss_oz;
  }
  const int n0 = nt * 128;

  __shared__ __align__(16) bf16 As[128 * LDA];
  __shared__ __align__(16) bf16 Bs[128 * LDA];

  const int arow = tid >> 1, acol = (tid & 1) * 16;
  int ar = row0 + arow; if (ar >= cnt) ar = cnt - 1;
  const bf16* aptr = abuf + (size_t)(base + ar) * 1024 + acol;
  bf16* const alds = As + arow * LDA + acol;

  const int brow = tid >> 1, bcol = (tid & 1) * 16;
  int bn = n0 + brow; if (bn > 1022) bn = 1022;
  const float* bptr = wp + (size_t)bn * 1024 + bcol;
  bf16* const blds = Bs + brow * LDA + bcol;

  const int wid = tid >> 6, lane = tid & 63;
  const int wr = (wid >> 1) * 64, wc = (wid & 1) * 64;
  const int lrow = lane & 15, quad = lane >> 4;

  const floatx4 fz = {0.f, 0.f, 0.f, 0.f};
  floatx4 acc[4][4];
#pragma unroll
  for (int mi = 0; mi < 4; ++mi)
#pragma unroll
    for (int ni = 0; ni < 4; ++ni) acc[mi][ni] = fz;

  uint4  a0 = *(const uint4*)(aptr);
  uint4  a1 = *(const uint4*)(aptr + 8);
  float4 f0 = *(const float4*)(bptr);
  float4 f1 = *(const float4*)(bptr + 4);
  float4 f2 = *(const float4*)(bptr + 8);
  float4 f3 = *(const float4*)(bptr + 12);

  for (int k0 = 0; k0 < 1024; k0 += 32) {
    __syncthreads();
    *(uint4*)alds       = a0;
    *(uint4*)(alds + 8) = a1;
    *(uint4*)blds       = pack_bf8(f0, f1);
    *(uint4*)(blds + 8) = pack_bf8(f2, f3);
    __syncthreads();
    const int kn = (k0 + 32 < 1024) ? (k0 + 32) : 0;
    a0 = *(const uint4*)(aptr + kn);
    a1 = *(const uint4*)(aptr + kn + 8);
    f0 = *(const float4*)(bptr + kn);
    f1 = *(const float4*)(bptr + kn + 4);
    f2 = *(const float4*)(bptr + kn + 8);
    f3 = *(const float4*)(bptr + kn + 12);

    bf16x8 af[4], bf_[4];
#pragma unroll
    for (int mi = 0; mi < 4; ++mi)
      af[mi] = *(const bf16x8*)(As + (wr + mi * 16 + lrow) * LDA + quad * 8);
#pragma unroll
    for (int ni = 0; ni < 4; ++ni)
      bf_[ni] = *(const bf16x8*)(Bs + (wc + ni * 16 + lrow) * LDA + quad * 8);
#pragma unroll
    for (int mi = 0; mi < 4; ++mi)
#pragma unroll
      for (int ni = 0; ni < 4; ++ni)
        acc[mi][ni] = __builtin_amdgcn_mfma_f32_16x16x32_bf16(af[mi], bf_[ni], acc[mi][ni], 0, 0, 0);
  }

  const int mbase = base + row0;
#pragma unroll
  for (int mi = 0; mi < 4; ++mi) {
#pragma unroll
    for (int r = 0; r < 4; ++r) {
      const int row = wr + mi * 16 + quad * 4 + r;
      const bool rowok = (row0 + row) < cnt;
      float ssum = 0.f;
#pragma unroll
      for (int ni = 0; ni < 4; ++ni) {
        const float v = acc[mi][ni][r];
        const int n = n0 + wc + ni * 16 + lrow;
        if (rowok && n < 1023) {
          obuf[(size_t)(mbase + row) * 1024 + n] = v;
          ssum += v * v;
        }
      }
      ssum += __shfl_xor(ssum, 1);
      ssum += __shfl_xor(ssum, 2);
      ssum += __shfl_xor(ssum, 4);
      ssum += __shfl_xor(ssum, 8);
      if (lrow == 0 && rowok) atomicAdd(ssbuf + mbase + row, ssum);
    }
  }
}

// ---------------- final LResNet combine + Lorentz normalize ----------------
__global__ __launch_bounds__(256) void combine_kernel(
    const float* __restrict__ o_r, const float* __restrict__ o_s,
    const float* __restrict__ ss_or, const float* __restrict__ ss_oz,
    const int* __restrict__ pos_of, const float* __restrict__ wgt,
    float* __restrict__ out)
{
  const int t = blockIdx.x, tid = threadIdx.x;
  const int p = pos_of[t];
  const float w = wgt[t];
  const float4 oz = ((const float4*)(o_s + (size_t)t * 1024))[tid];
  const float4 oe = ((const float4*)(o_r + (size_t)p * 1024))[tid];
  const float tw = 2.f * w;
  float c0 = oz.x + tw * oe.x;
  float c1 = oz.y + tw * oe.y;
  float c2 = oz.z + tw * oe.z;
  float c3 = (tid == 255) ? 0.f : (oz.w + tw * oe.w);  // n=1023 is padding
  float ssum = c0 * c0 + c1 * c1 + c2 * c2 + c3 * c3;
#pragma unroll
  for (int off = 32; off > 0; off >>= 1) ssum += __shfl_down(ssum, off);
  __shared__ float rs[4];
  if ((tid & 63) == 0) rs[tid >> 6] = ssum;
  __syncthreads();
  const float space2 = rs[0] + rs[1] + rs[2] + rs[3];
  const float comb0 = sqrtf(ss_oz[t] + 1.f) + 2.f + 2.f * w * sqrtf(ss_or[p] + 1.f);
  const float li = space2 - comb0 * comb0;
  const float inv = 1.f / sqrtf(fmaxf(fabsf(li), 1e-8f));
  float* orow = out + (size_t)t * 1024;
  const int j = 1 + tid * 4;
  orow[j]     = c0 * inv;
  orow[j + 1] = c1 * inv;
  orow[j + 2] = c2 * inv;
  if (tid != 255) orow[j + 3] = c3 * inv;
  if (tid == 0) orow[0] = comb0 * inv;
}

extern "C" void kernel_launch(void* const* d_in, const int* in_sizes, int n_in,
                              void* d_out, int out_size, void* d_ws, size_t ws_size,
                              hipStream_t stream) {
  const float* x      = (const float*)d_in[0];
  const float* gate_w = (const float*)d_in[1];
  const float* gate_b = (const float*)d_in[2];
  const float* W1     = (const float*)d_in[3];
  const float* W3     = (const float*)d_in[4];
  const float* W2     = (const float*)d_in[5];
  const float* Ws1    = (const float*)d_in[6];
  const float* Ws3    = (const float*)d_in[7];
  const float* Ws2    = (const float*)d_in[8];
  float* out = (float*)d_out;

  char* ws = (char*)d_ws;
  size_t off = 0;
  auto alloc = [&](size_t bytes) {
    void* p = ws + off;
    off += (bytes + 255) & ~(size_t)255;
    return p;
  };
  bf16*  x_bf = (bf16*) alloc((size_t)TOK * 1024 * 2);
  bf16*  h_r  = (bf16*) alloc((size_t)TOK * 1024 * 2);
  bf16*  h_s  = (bf16*) alloc((size_t)TOK * 1024 * 2);
  float* o_r  = (float*)alloc((size_t)TOK * 1024 * 4);
  float* o_s  = (float*)alloc((size_t)TOK * 1024 * 4);
  float* ss   = (float*)alloc((size_t)4 * TOK * 4);  // ss_r, ss_z, ss_or, ss_oz
  int*   eidx = (int*)  alloc((size_t)TOK * 4);
  float* ewgt = (float*)alloc((size_t)TOK * 4);
  int*   perm = (int*)  alloc((size_t)TOK * 4);
  int*   posf = (int*)  alloc((size_t)TOK * 4);
  int*   segb = (int*)  alloc(64);

  float* ss_r  = ss;
  float* ss_z  = ss + TOK;
  float* ss_or = ss + 2 * TOK;
  float* ss_oz = ss + 3 * TOK;

  hipMemsetAsync(ss, 0, (size_t)4 * TOK * 4, stream);
  gate_cvt_kernel<<<TOK, 256, 0, stream>>>(x, gate_w, gate_b, x_bf, eidx, ewgt);
  route_kernel<<<1, 256, 0, stream>>>(eidx, perm, posf, segb);
  mlp1_kernel<<<dim3(16, 144), 256, 0, stream>>>(x_bf, W1, W3, Ws1, Ws3, perm, segb,
                                                 h_r, h_s, ss_r, ss_z);
  finalize_t_kernel<<<8, 256, 0, stream>>>(ss_r, ss_z, h_r, h_s);
  mlp2_kernel<<<dim3(8, 144), 256, 0, stream>>>(h_r, h_s, W2, Ws2, segb,
                                                o_r, o_s, ss_or, ss_oz);
  combine_kernel<<<TOK, 256, 0, stream>>>(o_r, o_s, ss_or, ss_oz, posf, ewgt, out);
}